// Round 6
// baseline (389699.463 us; speedup 1.0000x reference)
//
#include <hip/hip_runtime.h>

// ============================================================================
// Persistent pipelined LSTM-with-projection, fp32, MI355X (gfx950).
//
// R6 changes vs R5 (which passed at 61ms, VALUBusy 18.9%):
//  (A) Re-vectorize all communication paths. R5's scalarization doubled
//      SQ_LDS_BANK_CONFLICT to 4.5e9 (~7ms): scalar ring-commit stores hit
//      banks =0 mod 4 only (8-way). Now: cross-WG global data moves as 8-byte
//      relaxed-AGENT atomics (compiler emits global_load/store_dwordx2 with
//      correct sc bits AND tracks vmcnt -- same mechanism R5 proved coherent),
//      LDS commits are b128 again (R3's conflict-clean pattern).
//  (B) Projection prefetch depth 1 -> 4 (4 register sets, fully unrolled so
//      all indexing is compile-time): wait distance ~3 iters (~660cyc) covers
//      ~600cyc L3 latency; R5 exposed ~470cyc x 32 chunks (~6us/step).
// Everything else identical to R5.
// ============================================================================

#define B_    64
#define T_    1024
#define P_    256
#define H_    1024
#define L_    4
#define G4_   4096
#define NTHR  256
#define WWIN  8                     // h ring slots (power of two)
#define HSLOT (P_ * B_)             // 16384 floats per slot, layout [p][b]

#define LDS_W     (512 * 64)        // 131072 B, k-major, swizzled rows
#define LDS_XH    4096              // 16 KB: GEMM staging; proj arena (w/ ACT)
#define LDS_ACT   1024              // act [16 cells][64 b]
#define LDS_FLOATS (LDS_W + LDS_XH + LDS_ACT)
#define LDS_BYTES  (LDS_FLOATS * 4) // 151552 B

// projection arena overlays XH+ACT (both dead during proj): 4896 <= 5120
#define PA_CH  36                   // padded row: 32 j + 4
#define PA_BUF (64 * PA_CH)         // 2304 floats per act chunk buffer
#define PW_OFF (2 * PA_BUF)         // 4608: two Whr chunk buffers of 144
#define PW_BUF (4 * PA_CH)          // 144

#define ACT_FLOATS ((size_t)L_ * H_ * B_)        // 1 MB act broadcast bufs

struct alignas(16) F4 { float f[4]; };

// ---- cross-WG data movement: compiler-tracked agent-scope accesses ---------
// 8-byte relaxed AGENT atomics: hardware-coherent at the device coherence
// point (same semantics as R5's scalar version, half the instructions).
__device__ __forceinline__ void lda2(const float* p, float& a, float& b) {
  union { double d; float f[2]; } u;
  u.d = __hip_atomic_load((const double*)p, __ATOMIC_RELAXED,
                          __HIP_MEMORY_SCOPE_AGENT);
  a = u.f[0]; b = u.f[1];
}
__device__ __forceinline__ void sta2(float* p, float a, float b) {
  union { double d; float f[2]; } u;
  u.f[0] = a; u.f[1] = b;
  __hip_atomic_store((double*)p, u.d, __ATOMIC_RELAXED,
                     __HIP_MEMORY_SCOPE_AGENT);
}
__device__ __forceinline__ void sta(float* p, float v) {
  __hip_atomic_store(p, v, __ATOMIC_RELAXED, __HIP_MEMORY_SCOPE_AGENT);
}
__device__ __forceinline__ void drain_vm() {   // conservative release: drain all
  asm volatile("s_waitcnt vmcnt(0)" ::: "memory");
}

__device__ __forceinline__ float fsig(float x) {
  float e = __expf(-x);                        // saturation-safe
  return __builtin_amdgcn_rcpf(1.0f + e);
}
__device__ __forceinline__ float ftanh(float x) {
  float ax = fabsf(x);
  float e  = __expf(-2.0f * ax);               // in (0,1] -> no overflow/NaN
  float r  = (1.0f - e) * __builtin_amdgcn_rcpf(1.0f + e);
  return copysignf(r, x);
}
__device__ __forceinline__ float qsum(float v) {
  v += __int_as_float(__builtin_amdgcn_update_dpp(
        0, __float_as_int(v), 0xB1, 0xF, 0xF, false)); // [1,0,3,2]
  v += __int_as_float(__builtin_amdgcn_update_dpp(
        0, __float_as_int(v), 0x4E, 0xF, 0xF, false)); // [2,3,0,1]
  return v;
}
// wave 0 polls 64 flags; others park at the barrier.
__device__ __forceinline__ void wait1(int* f, int tid, int target) {
  if (tid < 64) {
    while (true) {
      int v = __hip_atomic_load(&f[tid], __ATOMIC_RELAXED, __HIP_MEMORY_SCOPE_AGENT);
      if (__ballot(v < target) == 0ull) break;
      __builtin_amdgcn_s_sleep(2);
    }
  }
  __syncthreads();
  asm volatile("" ::: "memory");   // compiler barrier: no hoisting data loads
}

extern "C" __global__ void __launch_bounds__(NTHR, 1)
lstm_persistent(const float* __restrict__ y,
                const float* __restrict__ Wih,
                const float* __restrict__ Whh,
                const float* __restrict__ bih,
                const float* __restrict__ bhh,
                const float* __restrict__ Whr,
                const int*   __restrict__ mslp,
                float*       __restrict__ out,
                float*       __restrict__ hbuf,
                float*       __restrict__ actg,
                int*         __restrict__ hflag,
                int*         __restrict__ pflag)
{
  extern __shared__ float lds[];
  float* Ws   = lds;
  float* XH   = lds + LDS_W;
  float* ACT  = XH + LDS_XH;
  float* PRJ  = XH;                 // proj arena: 4896 floats over XH+ACT

  const int bid = blockIdx.x;
  const int l   = (bid & 7) >> 1;   // layer on XCD pair {2l,2l+1}
  const int w   = ((bid & 1)) + 2 * (bid >> 3);   // 0..63, bijective
  const int J0  = w * 16;
  const int tid  = threadIdx.x;
  const int msl  = mslp[0];

  // ---- one-time: gate-weight slice (k-major, swizzled) into LDS -----------
  {
    const float* wih_l = Wih + (size_t)l * G4_ * P_;
    const float* whh_l = Whh + (size_t)l * G4_ * P_;
    for (int it = 0; it < 32; ++it) {
      int idx4 = tid + NTHR * it;            // 8192 F4 total
      int r    = idx4 >> 7;                  // 0..63, r = 4*cell + gate
      int k4   = (idx4 & 127) << 2;          // 0..508
      int g = r & 3, j = r >> 2;
      int grow = g * H_ + J0 + j;            // torch gate order i,f,g,o
      F4 v;
      if (k4 < 256) v = *(const F4*)&wih_l[(size_t)grow * P_ + k4];
      else          v = *(const F4*)&whh_l[(size_t)grow * P_ + (k4 - 256)];
#pragma unroll
      for (int i = 0; i < 4; ++i)
        Ws[(size_t)(k4 + i) * 64 + (r ^ (4 * (i & 1)))] = v.f[i];
    }
  }
  __syncthreads();

  // ---- thread mappings ----------------------------------------------------
  const int w4   = tid >> 6;            // wave 0..3
  const int lane = tid & 63;
  const int c16  = lane >> 2;           // 0..15
  const int ksub = lane & 3;            // k-split lane within quad
  const int lr   = (w4 << 1) | (c16 >> 3);   // rows 8lr..8lr+7
  const int lb   = c16 & 7;                  // b 8lb..8lb+7
  const int swz  = 4 * (ksub & 1);
  // GEMM staging (transpose path, layer-0 y):
  const int sb0 = tid >> 3, skq = tid & 7, skl = skq << 2;
  // GEMM staging (fast path, h ring [p][b]):
  const int kidx = tid >> 3, bq = tid & 7;
  // act repack / proj staging:
  const int jqr = tid >> 6, b_r = tid & 63;
  // proj compute:
  const int b_p = (w4 << 4) | (tid & 15);
  const int pw  = (tid >> 4) & 3;
  // proj Whr staging (threads 0..31 only):
  const int pws = tid >> 3, jqlw = tid & 7;   // valid when tid < 32

  float* hsrc = hbuf + (size_t)l * (WWIN * HSLOT);
  const float* hprv = (l > 0) ? (hbuf + (size_t)(l - 1) * (WWIN * HSLOT)) : hbuf;
  float* AGf = actg + (size_t)l * H_ * B_;   // [jq 0..255][b 0..63] of 4 floats

  // bias straight to registers (own 8 rows)
  float biasr[8];
#pragma unroll
  for (int i = 0; i < 8; ++i) {
    int r = 8 * lr + i, g = r & 3, j = r >> 2;
    int grow = g * H_ + J0 + j;
    biasr[i] = bih[l * G4_ + grow] + bhh[l * G4_ + grow];
  }

  float cst[2][2] = {{0.f, 0.f}, {0.f, 0.f}};

  for (int t = 0; t < T_; ++t) {
    float acc[8][8];
#pragma unroll
    for (int i = 0; i < 8; ++i)
#pragma unroll
      for (int jx = 0; jx < 8; ++jx) acc[i][jx] = 0.f;

    auto gemm_chunk = [&](int cc) {
      const float* buf = XH + ((cc & 1) << 11);
      const int kb = cc << 5;
#pragma unroll
      for (int jj = 0; jj < 8; ++jj) {
        const int kl = 4 * jj + ksub;
        const float* wrow = Ws + (size_t)(kb + kl) * 64;
        F4 wlo = *(const F4*)&wrow[(8 * lr) ^ swz];
        F4 whi = *(const F4*)&wrow[(8 * lr + 4) ^ swz];
        const int sx = (4 * jj) ^ swz;                  // kl&28 = 4*jj
        const float* xrow = buf + kl * 64;
        F4 xlo = *(const F4*)&xrow[(8 * lb) ^ sx];
        F4 xhi = *(const F4*)&xrow[(8 * lb + 4) ^ sx];
#pragma unroll
        for (int i = 0; i < 4; ++i)
#pragma unroll
          for (int jx = 0; jx < 4; ++jx) {
            acc[i][jx]         = fmaf(wlo.f[i], xlo.f[jx], acc[i][jx]);
            acc[i][jx + 4]     = fmaf(wlo.f[i], xhi.f[jx], acc[i][jx + 4]);
            acc[i + 4][jx]     = fmaf(whi.f[i], xlo.f[jx], acc[i + 4][jx]);
            acc[i + 4][jx + 4] = fmaf(whi.f[i], xhi.f[jx], acc[i + 4][jx + 4]);
          }
      }
    };

    // ---- h-ring staging: issue (dwordx2 agent loads), commit (b128) ------
    float rg[8];
    auto ring_issue = [&](const float* src, int cc) {
      const int koff = (cc & 7) << 5;
      const float* pb = src + (size_t)(koff + kidx) * 64 + 4 * bq;
      lda2(pb + 0,  rg[0], rg[1]);
      lda2(pb + 2,  rg[2], rg[3]);
      lda2(pb + 32, rg[4], rg[5]);
      lda2(pb + 34, rg[6], rg[7]);
    };
    auto ring_commit = [&](float* dst) {
      const int sx = (kidx & 28) ^ (4 * (kidx & 1));
      F4 a, b;
#pragma unroll
      for (int i = 0; i < 4; ++i) { a.f[i] = rg[i]; b.f[i] = rg[4 + i]; }
      *(F4*)&dst[kidx * 64 + ((4 * bq) ^ sx)]      = a;
      *(F4*)&dst[kidx * 64 + ((4 * bq + 32) ^ sx)] = b;
    };
    // layer-0 y staging (plain cached loads, transpose)
    auto stage_y = [&](int cc, float* dst) {
      const int koff = (cc & 7) << 5;
      F4 ra  = *(const F4*)(y + ((size_t)sb0 * T_ + t) * P_ + koff + skl);
      F4 rb4 = *(const F4*)(y + ((size_t)(sb0 + 32) * T_ + t) * P_ + koff + skl);
#pragma unroll
      for (int i2 = 0; i2 < 4; ++i2) {
        const int sw = (skq << 2) ^ (4 * (i2 & 1));
        dst[(skl + i2) * 64 + (sb0 ^ sw)]        = ra.f[i2];
        dst[(skl + i2) * 64 + ((sb0 + 32) ^ sw)] = rb4.f[i2];
      }
    };

    // ---- x-half of gate GEMM ---------------------------------------------
    if (l > 0) wait1(hflag + (l - 1) * 64, tid, t);
    if (l == 0) {
      stage_y(0, XH);
      __syncthreads();
      for (int cc = 0; cc < 8; ++cc) {
        if (cc < 7) stage_y(cc + 1, XH + (((cc + 1) & 1) << 11));
        gemm_chunk(cc);
        __syncthreads();
      }
    } else {
      const float* xp = hprv + (size_t)(t & (WWIN - 1)) * HSLOT;
      ring_issue(xp, 0);
      ring_commit(XH);
      __syncthreads();
      for (int cc = 0; cc < 8; ++cc) {
        if (cc < 7) ring_issue(xp, cc + 1);
        gemm_chunk(cc);
        if (cc < 7) ring_commit(XH + (((cc + 1) & 1) << 11));
        __syncthreads();
      }
    }
    // ---- h-half (recurrent critical path) --------------------------------
    if (t > 0) {
      wait1(hflag + l * 64, tid, t - 1);
      const float* hp = hsrc + (size_t)((t - 1) & (WWIN - 1)) * HSLOT;
      ring_issue(hp, 8);
      ring_commit(XH);
      __syncthreads();
      for (int cc = 8; cc < 16; ++cc) {
        if (cc < 15) ring_issue(hp, cc + 1);
        gemm_chunk(cc);
        if (cc < 15) ring_commit(XH + (((cc + 1) & 1) << 11));
        __syncthreads();
      }
    }

    // ---- combine k-split partials across lane quads (VALU-only) ----------
#pragma unroll
    for (int i = 0; i < 8; ++i)
#pragma unroll
      for (int jx = 0; jx < 8; ++jx) acc[i][jx] = qsum(acc[i][jx]);

    // ---- activations + cell update ---------------------------------------
#pragma unroll
    for (int m = 0; m < 2; ++m)
#pragma unroll
      for (int n = 0; n < 2; ++n) {
#define MUX(I) ((ksub & 2) ? ((ksub & 1) ? acc[I][6 + n] : acc[I][4 + n])  \
                           : ((ksub & 1) ? acc[I][2 + n] : acc[I][0 + n]))
        float vi = MUX(4 * m + 0) + biasr[4 * m + 0];
        float vf = MUX(4 * m + 1) + biasr[4 * m + 1];
        float vg = MUX(4 * m + 2) + biasr[4 * m + 2];
        float vo = MUX(4 * m + 3) + biasr[4 * m + 3];
#undef MUX
        float ig = fsig(vi), fg = fsig(vf), gg = ftanh(vg), og = fsig(vo);
        float cn = fmaf(fg, cst[m][n], ig * gg);
        cst[m][n] = cn;
        ACT[(2 * lr + m) * 64 + (8 * lb + 2 * ksub + n)] = og * ftanh(cn);
      }
    __syncthreads();

    // ---- broadcast acts: LDS -> global [jq][b][4], dwordx2 agent stores --
    {
      float a0 = ACT[(4 * jqr + 0) * 64 + b_r];
      float a1 = ACT[(4 * jqr + 1) * 64 + b_r];
      float a2 = ACT[(4 * jqr + 2) * 64 + b_r];
      float a3 = ACT[(4 * jqr + 3) * 64 + b_r];
      float* dst = AGf + ((size_t)(4 * w + jqr) * 64 + b_r) * 4;
      sta2(dst + 0, a0, a1);
      sta2(dst + 2, a2, a3);
    }
    drain_vm();          // release: own stores complete at coherence point
    __syncthreads();     // all waves drained
    if (tid == 0)
      __hip_atomic_store(&pflag[l * 64 + w], t, __ATOMIC_RELAXED, __HIP_MEMORY_SCOPE_AGENT);

    // ---- projection: h[b][4w+pw] = sum_j act[j][b]*Whr[4w+pw][j] ---------
    // Depth-4 register pipeline (fully unrolled: compile-time set indices);
    // wait distance ~3 iterations covers L3 latency; compiler tracks vmcnt.
    wait1(pflag + l * 64, tid, t);

    float ar[4][8]; F4 wrs[4];
    auto proj_issue = [&](int ch, int s) {
      const float* a0 = AGf + ((size_t)(8 * ch + 2 * jqr) * 64 + b_r) * 4;
      lda2(a0 + 0,   ar[s][0], ar[s][1]);
      lda2(a0 + 2,   ar[s][2], ar[s][3]);
      lda2(a0 + 256, ar[s][4], ar[s][5]);
      lda2(a0 + 258, ar[s][6], ar[s][7]);
      if (tid < 32)      // Whr is read-only input: plain cached load
        wrs[s] = *(const F4*)(Whr + ((size_t)(l * P_ + 4 * w + pws)) * H_
                              + 32 * ch + 4 * jqlw);
    };
    auto proj_commit = [&](int ch, int s) {
      float* ab = PRJ + (ch & 1) * PA_BUF;
      F4 lo, hi;
#pragma unroll
      for (int i = 0; i < 4; ++i) { lo.f[i] = ar[s][i]; hi.f[i] = ar[s][4 + i]; }
      *(F4*)&ab[b_r * PA_CH + 8 * jqr]     = lo;
      *(F4*)&ab[b_r * PA_CH + 8 * jqr + 4] = hi;
      if (tid < 32)
        *(F4*)&(PRJ + PW_OFF + (ch & 1) * PW_BUF)[pws * PA_CH + 4 * jqlw] = wrs[s];
    };

    float s = 0.f;
    proj_issue(0, 0); proj_issue(1, 1); proj_issue(2, 2);
    proj_commit(0, 0);
    __syncthreads();
#pragma unroll
    for (int ch = 0; ch < 32; ++ch) {
      const float* ab = PRJ + (ch & 1) * PA_BUF + b_p * PA_CH;
      const float* wb = PRJ + PW_OFF + (ch & 1) * PW_BUF + pw * PA_CH;
#pragma unroll
      for (int jj = 0; jj < 8; ++jj) {
        F4 a  = *(const F4*)&ab[4 * jj];
        F4 wv = *(const F4*)&wb[4 * jj];
        s = fmaf(a.f[0], wv.f[0], s);
        s = fmaf(a.f[1], wv.f[1], s);
        s = fmaf(a.f[2], wv.f[2], s);
        s = fmaf(a.f[3], wv.f[3], s);
      }
      if (ch + 1 < 32) proj_commit(ch + 1, (ch + 1) & 3);
      if (ch + 3 < 32) proj_issue(ch + 3, (ch + 3) & 3);
      __syncthreads();
    }

    // ---- emit h (ring, agent store) + output -----------------------------
    if (l < 3) wait1(hflag + (l + 1) * 64, tid, t - WWIN);   // ring back-pressure
    sta(hsrc + (size_t)(t & (WWIN - 1)) * HSLOT + (size_t)(4 * w + pw) * 64 + b_p, s);
    if (l == 3 && t >= msl)
      out[((size_t)b_p * (T_ - msl) + (t - msl)) * P_ + 4 * w + pw] = s;
    drain_vm();          // release h
    __syncthreads();
    if (tid == 0)
      __hip_atomic_store(&hflag[l * 64 + w], t, __ATOMIC_RELAXED, __HIP_MEMORY_SCOPE_AGENT);
  }
}

extern "C" void kernel_launch(void* const* d_in, const int* in_sizes, int n_in,
                              void* d_out, int out_size, void* d_ws, size_t ws_size,
                              hipStream_t stream) {
  const float* y   = (const float*)d_in[0];
  const float* Wih = (const float*)d_in[1];
  const float* Whh = (const float*)d_in[2];
  const float* bih = (const float*)d_in[3];
  const float* bhh = (const float*)d_in[4];
  const float* Whr = (const float*)d_in[5];
  const int*   msl = (const int*)d_in[6];
  float* out = (float*)d_out;

  // ws: [flags 4KB][act broadcast 1MB][h ring 2MB]  (~3 MB total)
  char*  ws    = (char*)d_ws;
  int*   flags = (int*)ws;
  float* actg  = (float*)(ws + 4096);
  float* hbuf  = (float*)(ws + 4096 + ACT_FLOATS * sizeof(float));

  hipMemsetAsync(flags, 0xFF, 4096, stream);   // epoch counters start at -1

  hipFuncSetAttribute(reinterpret_cast<const void*>(&lstm_persistent),
                      hipFuncAttributeMaxDynamicSharedMemorySize, LDS_BYTES);

  lstm_persistent<<<dim3(L_ * 64), dim3(NTHR), LDS_BYTES, stream>>>(
      y, Wih, Whh, bih, bhh, Whr, msl, out,
      hbuf, actg, flags /*hflag*/, flags + 256 /*pflag*/);
}

// Round 7
// 50680.054 us; speedup vs baseline: 7.6894x; 7.6894x over previous
//
#include <hip/hip_runtime.h>

// ============================================================================
// Persistent pipelined LSTM-with-projection, fp32, MI355X (gfx950).
//
// R7 changes vs R6 (390ms, spill catastrophe) / R5 (61ms, last good):
//  (A) KEEP R6's vectorization: dwordx2 relaxed-AGENT atomics for cross-WG
//      global data + b128 LDS commits (bank conflicts 4.5e9 -> 2.16e9 ✓).
//  (B) REVERT depth-4 proj unroll (VGPR 256 + 691 GB scratch spill traffic
//      = the 390ms). Depth-2 with NAMED F4 register sets, x2 interleaved
//      loop -- all indices compile-time, ~190 VGPR.
//  (C) Raw barriers in the hot loops: s_waitcnt lgkmcnt(0); s_barrier
//      (inline asm). __syncthreads() makes the compiler drain vmcnt(0) at
//      every barrier, killing all prefetch; that drain was ~48 x ~1us/step
//      = R5's entire 50us stall. LDS visibility needs only lgkmcnt. The
//      compiler still inserts vmcnt waits before each load's USE (register
//      dependence tracking), so prefetches stay correct across barriers --
//      no manual vmcnt counting (the R4 failure).
// Full vmcnt drains remain ONLY at the two release points (act flag, h flag).
// ============================================================================

#define B_    64
#define T_    1024
#define P_    256
#define H_    1024
#define L_    4
#define G4_   4096
#define NTHR  256
#define WWIN  8                     // h ring slots (power of two)
#define HSLOT (P_ * B_)             // 16384 floats per slot, layout [p][b]

#define LDS_W     (512 * 64)        // 131072 B, k-major, swizzled rows
#define LDS_XH    4096              // 16 KB: GEMM staging; proj arena (w/ ACT)
#define LDS_ACT   1024              // act [16 cells][64 b]
#define LDS_FLOATS (LDS_W + LDS_XH + LDS_ACT)
#define LDS_BYTES  (LDS_FLOATS * 4) // 151552 B

// projection arena overlays XH+ACT (both dead during proj): 4896 <= 5120
#define PA_CH  36                   // padded row: 32 j + 4
#define PA_BUF (64 * PA_CH)         // 2304 floats per act chunk buffer
#define PW_OFF (2 * PA_BUF)         // 4608: two Whr chunk buffers of 144
#define PW_BUF (4 * PA_CH)          // 144

#define ACT_FLOATS ((size_t)L_ * H_ * B_)        // 1 MB act broadcast bufs

struct alignas(16) F4 { float f[4]; };

// ---- cross-WG data movement: compiler-tracked agent-scope accesses ---------
__device__ __forceinline__ void lda2(const float* p, float& a, float& b) {
  union { double d; float f[2]; } u;
  u.d = __hip_atomic_load((const double*)p, __ATOMIC_RELAXED,
                          __HIP_MEMORY_SCOPE_AGENT);
  a = u.f[0]; b = u.f[1];
}
__device__ __forceinline__ void sta2(float* p, float a, float b) {
  union { double d; float f[2]; } u;
  u.f[0] = a; u.f[1] = b;
  __hip_atomic_store((double*)p, u.d, __ATOMIC_RELAXED,
                     __HIP_MEMORY_SCOPE_AGENT);
}
__device__ __forceinline__ void sta(float* p, float v) {
  __hip_atomic_store(p, v, __ATOMIC_RELAXED, __HIP_MEMORY_SCOPE_AGENT);
}
__device__ __forceinline__ void drain_vm() {   // release: drain own stores
  asm volatile("s_waitcnt vmcnt(0)" ::: "memory");
}
// Hot-loop barrier: LDS visibility only -- does NOT drain vmcnt, so global
// prefetches survive. Compiler inserts vmcnt waits before each USE.
__device__ __forceinline__ void bar_lds() {
  asm volatile("s_waitcnt lgkmcnt(0)\n\ts_barrier" ::: "memory");
}

__device__ __forceinline__ float fsig(float x) {
  float e = __expf(-x);                        // saturation-safe
  return __builtin_amdgcn_rcpf(1.0f + e);
}
__device__ __forceinline__ float ftanh(float x) {
  float ax = fabsf(x);
  float e  = __expf(-2.0f * ax);               // in (0,1] -> no overflow/NaN
  float r  = (1.0f - e) * __builtin_amdgcn_rcpf(1.0f + e);
  return copysignf(r, x);
}
__device__ __forceinline__ float qsum(float v) {
  v += __int_as_float(__builtin_amdgcn_update_dpp(
        0, __float_as_int(v), 0xB1, 0xF, 0xF, false)); // [1,0,3,2]
  v += __int_as_float(__builtin_amdgcn_update_dpp(
        0, __float_as_int(v), 0x4E, 0xF, 0xF, false)); // [2,3,0,1]
  return v;
}
// wave 0 polls 64 flags; others park at the barrier.
__device__ __forceinline__ void wait1(int* f, int tid, int target) {
  if (tid < 64) {
    while (true) {
      int v = __hip_atomic_load(&f[tid], __ATOMIC_RELAXED, __HIP_MEMORY_SCOPE_AGENT);
      if (__ballot(v < target) == 0ull) break;
      __builtin_amdgcn_s_sleep(2);
    }
  }
  __syncthreads();
  asm volatile("" ::: "memory");   // no hoisting data loads above the wait
}

extern "C" __global__ void __launch_bounds__(NTHR, 1)
lstm_persistent(const float* __restrict__ y,
                const float* __restrict__ Wih,
                const float* __restrict__ Whh,
                const float* __restrict__ bih,
                const float* __restrict__ bhh,
                const float* __restrict__ Whr,
                const int*   __restrict__ mslp,
                float*       __restrict__ out,
                float*       __restrict__ hbuf,
                float*       __restrict__ actg,
                int*         __restrict__ hflag,
                int*         __restrict__ pflag)
{
  extern __shared__ float lds[];
  float* Ws   = lds;
  float* XH   = lds + LDS_W;
  float* ACT  = XH + LDS_XH;
  float* PRJ  = XH;                 // proj arena: 4896 floats over XH+ACT

  const int bid = blockIdx.x;
  const int l   = (bid & 7) >> 1;   // layer on XCD pair {2l,2l+1}
  const int w   = ((bid & 1)) + 2 * (bid >> 3);   // 0..63, bijective
  const int J0  = w * 16;
  const int tid  = threadIdx.x;
  const int msl  = mslp[0];

  // ---- one-time: gate-weight slice (k-major, swizzled) into LDS -----------
  {
    const float* wih_l = Wih + (size_t)l * G4_ * P_;
    const float* whh_l = Whh + (size_t)l * G4_ * P_;
    for (int it = 0; it < 32; ++it) {
      int idx4 = tid + NTHR * it;            // 8192 F4 total
      int r    = idx4 >> 7;                  // 0..63, r = 4*cell + gate
      int k4   = (idx4 & 127) << 2;          // 0..508
      int g = r & 3, j = r >> 2;
      int grow = g * H_ + J0 + j;            // torch gate order i,f,g,o
      F4 v;
      if (k4 < 256) v = *(const F4*)&wih_l[(size_t)grow * P_ + k4];
      else          v = *(const F4*)&whh_l[(size_t)grow * P_ + (k4 - 256)];
#pragma unroll
      for (int i = 0; i < 4; ++i)
        Ws[(size_t)(k4 + i) * 64 + (r ^ (4 * (i & 1)))] = v.f[i];
    }
  }
  __syncthreads();

  // ---- thread mappings ----------------------------------------------------
  const int w4   = tid >> 6;            // wave 0..3
  const int lane = tid & 63;
  const int c16  = lane >> 2;           // 0..15
  const int ksub = lane & 3;            // k-split lane within quad
  const int lr   = (w4 << 1) | (c16 >> 3);   // rows 8lr..8lr+7
  const int lb   = c16 & 7;                  // b 8lb..8lb+7
  const int swz  = 4 * (ksub & 1);
  // GEMM staging (transpose path, layer-0 y):
  const int sb0 = tid >> 3, skq = tid & 7, skl = skq << 2;
  // GEMM staging (fast path, h ring [p][b]):
  const int kidx = tid >> 3, bq = tid & 7;
  // act repack / proj staging:
  const int jqr = tid >> 6, b_r = tid & 63;
  // proj compute:
  const int b_p = (w4 << 4) | (tid & 15);
  const int pw  = (tid >> 4) & 3;
  // proj Whr staging (threads 0..31 only):
  const int pws = tid >> 3, jqlw = tid & 7;   // valid when tid < 32

  float* hsrc = hbuf + (size_t)l * (WWIN * HSLOT);
  const float* hprv = (l > 0) ? (hbuf + (size_t)(l - 1) * (WWIN * HSLOT)) : hbuf;
  float* AGf = actg + (size_t)l * H_ * B_;   // [jq 0..255][b 0..63] of 4 floats

  float biasr[8];
#pragma unroll
  for (int i = 0; i < 8; ++i) {
    int r = 8 * lr + i, g = r & 3, j = r >> 2;
    int grow = g * H_ + J0 + j;
    biasr[i] = bih[l * G4_ + grow] + bhh[l * G4_ + grow];
  }

  float cst[2][2] = {{0.f, 0.f}, {0.f, 0.f}};

  for (int t = 0; t < T_; ++t) {
    float acc[8][8];
#pragma unroll
    for (int i = 0; i < 8; ++i)
#pragma unroll
      for (int jx = 0; jx < 8; ++jx) acc[i][jx] = 0.f;

    auto gemm_chunk = [&](int cc) {
      const float* buf = XH + ((cc & 1) << 11);
      const int kb = cc << 5;
#pragma unroll
      for (int jj = 0; jj < 8; ++jj) {
        const int kl = 4 * jj + ksub;
        const float* wrow = Ws + (size_t)(kb + kl) * 64;
        F4 wlo = *(const F4*)&wrow[(8 * lr) ^ swz];
        F4 whi = *(const F4*)&wrow[(8 * lr + 4) ^ swz];
        const int sx = (4 * jj) ^ swz;                  // kl&28 = 4*jj
        const float* xrow = buf + kl * 64;
        F4 xlo = *(const F4*)&xrow[(8 * lb) ^ sx];
        F4 xhi = *(const F4*)&xrow[(8 * lb + 4) ^ sx];
#pragma unroll
        for (int i = 0; i < 4; ++i)
#pragma unroll
          for (int jx = 0; jx < 4; ++jx) {
            acc[i][jx]         = fmaf(wlo.f[i], xlo.f[jx], acc[i][jx]);
            acc[i][jx + 4]     = fmaf(wlo.f[i], xhi.f[jx], acc[i][jx + 4]);
            acc[i + 4][jx]     = fmaf(whi.f[i], xlo.f[jx], acc[i + 4][jx]);
            acc[i + 4][jx + 4] = fmaf(whi.f[i], xhi.f[jx], acc[i + 4][jx + 4]);
          }
      }
    };

    // ---- h-ring staging: issue (dwordx2 agent loads), commit (b128) ------
    F4 rgl, rgh;
    auto ring_issue = [&](const float* src, int cc) {
      const int koff = (cc & 7) << 5;
      const float* pb = src + (size_t)(koff + kidx) * 64 + 4 * bq;
      lda2(pb + 0,  rgl.f[0], rgl.f[1]);
      lda2(pb + 2,  rgl.f[2], rgl.f[3]);
      lda2(pb + 32, rgh.f[0], rgh.f[1]);
      lda2(pb + 34, rgh.f[2], rgh.f[3]);
    };
    auto ring_commit = [&](float* dst) {
      const int sx = (kidx & 28) ^ (4 * (kidx & 1));
      *(F4*)&dst[kidx * 64 + ((4 * bq) ^ sx)]      = rgl;
      *(F4*)&dst[kidx * 64 + ((4 * bq + 32) ^ sx)] = rgh;
    };
    // layer-0 y staging (plain cached loads, transpose)
    auto stage_y = [&](int cc, float* dst) {
      const int koff = (cc & 7) << 5;
      F4 ra  = *(const F4*)(y + ((size_t)sb0 * T_ + t) * P_ + koff + skl);
      F4 rb4 = *(const F4*)(y + ((size_t)(sb0 + 32) * T_ + t) * P_ + koff + skl);
#pragma unroll
      for (int i2 = 0; i2 < 4; ++i2) {
        const int sw = (skq << 2) ^ (4 * (i2 & 1));
        dst[(skl + i2) * 64 + (sb0 ^ sw)]        = ra.f[i2];
        dst[(skl + i2) * 64 + ((sb0 + 32) ^ sw)] = rb4.f[i2];
      }
    };

    // ---- x-half of gate GEMM ---------------------------------------------
    if (l > 0) wait1(hflag + (l - 1) * 64, tid, t);
    if (l == 0) {
      stage_y(0, XH);
      bar_lds();
      for (int cc = 0; cc < 8; ++cc) {
        if (cc < 7) stage_y(cc + 1, XH + (((cc + 1) & 1) << 11));
        gemm_chunk(cc);
        bar_lds();
      }
    } else {
      const float* xp = hprv + (size_t)(t & (WWIN - 1)) * HSLOT;
      ring_issue(xp, 0);
      ring_commit(XH);
      bar_lds();
      for (int cc = 0; cc < 8; ++cc) {
        if (cc < 7) ring_issue(xp, cc + 1);
        gemm_chunk(cc);
        if (cc < 7) ring_commit(XH + (((cc + 1) & 1) << 11));
        bar_lds();
      }
    }
    // ---- h-half (recurrent critical path) --------------------------------
    if (t > 0) {
      wait1(hflag + l * 64, tid, t - 1);
      const float* hp = hsrc + (size_t)((t - 1) & (WWIN - 1)) * HSLOT;
      ring_issue(hp, 8);
      ring_commit(XH);
      bar_lds();
      for (int cc = 8; cc < 16; ++cc) {
        if (cc < 15) ring_issue(hp, cc + 1);
        gemm_chunk(cc);
        if (cc < 15) ring_commit(XH + (((cc + 1) & 1) << 11));
        bar_lds();
      }
    }

    // ---- combine k-split partials across lane quads (VALU-only) ----------
#pragma unroll
    for (int i = 0; i < 8; ++i)
#pragma unroll
      for (int jx = 0; jx < 8; ++jx) acc[i][jx] = qsum(acc[i][jx]);

    // ---- activations + cell update ---------------------------------------
#pragma unroll
    for (int m = 0; m < 2; ++m)
#pragma unroll
      for (int n = 0; n < 2; ++n) {
#define MUX(I) ((ksub & 2) ? ((ksub & 1) ? acc[I][6 + n] : acc[I][4 + n])  \
                           : ((ksub & 1) ? acc[I][2 + n] : acc[I][0 + n]))
        float vi = MUX(4 * m + 0) + biasr[4 * m + 0];
        float vf = MUX(4 * m + 1) + biasr[4 * m + 1];
        float vg = MUX(4 * m + 2) + biasr[4 * m + 2];
        float vo = MUX(4 * m + 3) + biasr[4 * m + 3];
#undef MUX
        float ig = fsig(vi), fg = fsig(vf), gg = ftanh(vg), og = fsig(vo);
        float cn = fmaf(fg, cst[m][n], ig * gg);
        cst[m][n] = cn;
        ACT[(2 * lr + m) * 64 + (8 * lb + 2 * ksub + n)] = og * ftanh(cn);
      }
    bar_lds();

    // ---- broadcast acts: LDS -> global [jq][b][4], dwordx2 agent stores --
    {
      float a0 = ACT[(4 * jqr + 0) * 64 + b_r];
      float a1 = ACT[(4 * jqr + 1) * 64 + b_r];
      float a2 = ACT[(4 * jqr + 2) * 64 + b_r];
      float a3 = ACT[(4 * jqr + 3) * 64 + b_r];
      float* dst = AGf + ((size_t)(4 * w + jqr) * 64 + b_r) * 4;
      sta2(dst + 0, a0, a1);
      sta2(dst + 2, a2, a3);
    }
    drain_vm();          // release: own stores complete at coherence point
    __syncthreads();     // all waves drained
    if (tid == 0)
      __hip_atomic_store(&pflag[l * 64 + w], t, __ATOMIC_RELAXED, __HIP_MEMORY_SCOPE_AGENT);

    // ---- projection: h[b][4w+pw] = sum_j act[j][b]*Whr[4w+pw][j] ---------
    // Depth-2 register pipeline, NAMED F4 sets (no arrays -> no spills).
    wait1(pflag + l * 64, tid, t);

    F4 aAl, aAh, wA, aBl, aBh, wB;
    auto proj_issue = [&](int ch, F4& lo, F4& hi, F4& wv) {
      const float* a0 = AGf + ((size_t)(8 * ch + 2 * jqr) * 64 + b_r) * 4;
      lda2(a0 + 0,   lo.f[0], lo.f[1]);
      lda2(a0 + 2,   lo.f[2], lo.f[3]);
      lda2(a0 + 256, hi.f[0], hi.f[1]);
      lda2(a0 + 258, hi.f[2], hi.f[3]);
      if (tid < 32)      // Whr is read-only input: plain cached load
        wv = *(const F4*)(Whr + ((size_t)(l * P_ + 4 * w + pws)) * H_
                          + 32 * ch + 4 * jqlw);
    };
    auto proj_commit = [&](int bufi, F4& lo, F4& hi, F4& wv) {
      float* ab = PRJ + bufi * PA_BUF;
      *(F4*)&ab[b_r * PA_CH + 8 * jqr]     = lo;
      *(F4*)&ab[b_r * PA_CH + 8 * jqr + 4] = hi;
      if (tid < 32)
        *(F4*)&(PRJ + PW_OFF + bufi * PW_BUF)[pws * PA_CH + 4 * jqlw] = wv;
    };
    float s = 0.f;
    auto proj_comp = [&](int bufi) {
      const float* ab = PRJ + bufi * PA_BUF + b_p * PA_CH;
      const float* wb = PRJ + PW_OFF + bufi * PW_BUF + pw * PA_CH;
#pragma unroll
      for (int jj = 0; jj < 8; ++jj) {
        F4 a  = *(const F4*)&ab[4 * jj];
        F4 wv = *(const F4*)&wb[4 * jj];
        s = fmaf(a.f[0], wv.f[0], s);
        s = fmaf(a.f[1], wv.f[1], s);
        s = fmaf(a.f[2], wv.f[2], s);
        s = fmaf(a.f[3], wv.f[3], s);
      }
    };

    proj_issue(0, aAl, aAh, wA);
    proj_issue(1, aBl, aBh, wB);
    proj_commit(0, aAl, aAh, wA);
    bar_lds();
    for (int ch = 0; ch < 32; ch += 2) {
      // even: compute ch from buf0; commit ch+1 (B set -> buf1); refill A
      if (ch + 2 < 32) proj_issue(ch + 2, aAl, aAh, wA);
      proj_comp(0);
      if (ch + 1 < 32) proj_commit(1, aBl, aBh, wB);
      bar_lds();
      // odd: compute ch+1 from buf1; commit ch+2 (A set -> buf0); refill B
      if (ch + 3 < 32) proj_issue(ch + 3, aBl, aBh, wB);
      if (ch + 1 < 32) proj_comp(1);
      if (ch + 2 < 32) proj_commit(0, aAl, aAh, wA);
      bar_lds();
    }

    // ---- emit h (ring, agent store) + output -----------------------------
    if (l < 3) wait1(hflag + (l + 1) * 64, tid, t - WWIN);   // ring back-pressure
    sta(hsrc + (size_t)(t & (WWIN - 1)) * HSLOT + (size_t)(4 * w + pw) * 64 + b_p, s);
    if (l == 3 && t >= msl)
      out[((size_t)b_p * (T_ - msl) + (t - msl)) * P_ + 4 * w + pw] = s;
    drain_vm();          // release h
    __syncthreads();
    if (tid == 0)
      __hip_atomic_store(&hflag[l * 64 + w], t, __ATOMIC_RELAXED, __HIP_MEMORY_SCOPE_AGENT);
  }
}

extern "C" void kernel_launch(void* const* d_in, const int* in_sizes, int n_in,
                              void* d_out, int out_size, void* d_ws, size_t ws_size,
                              hipStream_t stream) {
  const float* y   = (const float*)d_in[0];
  const float* Wih = (const float*)d_in[1];
  const float* Whh = (const float*)d_in[2];
  const float* bih = (const float*)d_in[3];
  const float* bhh = (const float*)d_in[4];
  const float* Whr = (const float*)d_in[5];
  const int*   msl = (const int*)d_in[6];
  float* out = (float*)d_out;

  // ws: [flags 4KB][act broadcast 1MB][h ring 2MB]  (~3 MB total)
  char*  ws    = (char*)d_ws;
  int*   flags = (int*)ws;
  float* actg  = (float*)(ws + 4096);
  float* hbuf  = (float*)(ws + 4096 + ACT_FLOATS * sizeof(float));

  hipMemsetAsync(flags, 0xFF, 4096, stream);   // epoch counters start at -1

  hipFuncSetAttribute(reinterpret_cast<const void*>(&lstm_persistent),
                      hipFuncAttributeMaxDynamicSharedMemorySize, LDS_BYTES);

  lstm_persistent<<<dim3(L_ * 64), dim3(NTHR), LDS_BYTES, stream>>>(
      y, Wih, Whh, bih, bhh, Whr, msl, out,
      hbuf, actg, flags /*hflag*/, flags + 256 /*pflag*/);
}